// Round 7
// baseline (175.361 us; speedup 1.0000x reference)
//
#include <hip/hip_runtime.h>

// Problem constants (static in the reference: D1=D2=32, ADD1=ADD2=16, BATCH=8)
constexpr int FOCK_DIM = 4656;          // m*(m+1)/2 with m=96, 2 photons
constexpr int N        = 1024;          // D1*D2
constexpr int ROW_VEC  = FOCK_DIM / 4;  // 1164 float4 per output row
constexpr int B        = 8;             // batch
constexpr int TOTROWS  = B * FOCK_DIM;  // 37248 output rows
constexpr int GRID     = 2048;          // 8 blocks/CU on 256 CUs
constexpr int BLOCK    = 256;

typedef float f32x4 __attribute__((ext_vector_type(4)));
typedef int   i32x4 __attribute__((ext_vector_type(4)));

// Single kernel. Each block:
//  Phase A: builds inv[f] = i (fock->image inverse map) in its own LDS
//           (zero 4656 ints + scatter 1024 entries; ~5 iterations total,
//           amortized over ~18 rows of Phase B work).
//  Phase B: grid-strides over output rows (b, r). inv_lds[r] is a uniform
//           LDS broadcast resolved early; dead rows stream constant zeros
//           (same store morphology as the 6.8 TB/s fill); live rows gather
//           from the 4 KB input row through L1.
__global__ __launch_bounds__(BLOCK, 8) void fock_scatter_kernel(
    const float* __restrict__ in,
    const int*   __restrict__ fock_idx,
    float*       __restrict__ out) {

    __shared__ __align__(16) int inv_lds[FOCK_DIM];   // 18.6 KB -> 8 blocks/CU
    const int tid = threadIdx.x;

    // ---- Phase A: build inverse map in LDS ----
    i32x4* inv4_lds = reinterpret_cast<i32x4*>(inv_lds);
    {
        const i32x4 mone = {-1, -1, -1, -1};
        for (int t = tid; t < ROW_VEC; t += BLOCK) inv4_lds[t] = mone;
        __syncthreads();
        // 1024 entries, 4 per thread, coalesced int4 load
        const i32x4 fc = reinterpret_cast<const i32x4*>(fock_idx)[tid];
        inv_lds[fc.x] = 4 * tid + 0;
        inv_lds[fc.y] = 4 * tid + 1;
        inv_lds[fc.z] = 4 * tid + 2;
        inv_lds[fc.w] = 4 * tid + 3;
        __syncthreads();
    }

    // ---- Phase B: grid-stride over output rows ----
    for (int br = blockIdx.x; br < TOTROWS; br += GRID) {
        const int b = br / FOCK_DIM;          // magic-mul, once per row
        const int r = br - b * FOCK_DIM;
        const int x = inv_lds[r];             // uniform broadcast, ~120 cyc

        f32x4* __restrict__ orow =
            reinterpret_cast<f32x4*>(out + (size_t)br * FOCK_DIM);

        if (x < 0) {
            // dead row: pure constant store stream
            const f32x4 z = {0.f, 0.f, 0.f, 0.f};
            for (int c4 = tid; c4 < ROW_VEC; c4 += BLOCK) orow[c4] = z;
        } else {
            // live row: gather from 4 KB input row via L1
            const float* __restrict__ irow = in + ((size_t)b * N + (size_t)x) * N;
            for (int c4 = tid; c4 < ROW_VEC; c4 += BLOCK) {
                const i32x4 iv = inv4_lds[c4];
                f32x4 v;
                v.x = (iv.x >= 0) ? irow[iv.x] : 0.f;
                v.y = (iv.y >= 0) ? irow[iv.y] : 0.f;
                v.z = (iv.z >= 0) ? irow[iv.z] : 0.f;
                v.w = (iv.w >= 0) ? irow[iv.w] : 0.f;
                orow[c4] = v;
            }
        }
    }
}

extern "C" void kernel_launch(void* const* d_in, const int* in_sizes, int n_in,
                              void* d_out, int out_size, void* d_ws, size_t ws_size,
                              hipStream_t stream) {
    const float* in       = (const float*)d_in[0];   // [B, 1024, 1024] fp32
    const int*   fock_idx = (const int*)d_in[1];     // [1024] int32
    float*       out      = (float*)d_out;           // [B, 4656, 4656] fp32

    fock_scatter_kernel<<<GRID, BLOCK, 0, stream>>>(in, fock_idx, out);
}

// Round 8
// 165.603 us; speedup vs baseline: 1.0589x; 1.0589x over previous
//
#include <hip/hip_runtime.h>

// Problem constants (static in the reference: D1=D2=32, ADD1=ADD2=16, BATCH=8)
constexpr int FOCK_DIM = 4656;            // m*(m+1)/2 with m=96, 2 photons
constexpr int N        = 1024;            // D1*D2
constexpr int ROW_VEC  = FOCK_DIM / 4;    // 1164 float4 per output row
constexpr int B        = 8;               // batch
constexpr int ROWS_PER_BLK   = 8;         // 8 consecutive rows per 1024-thread block
constexpr int BLK_PER_BATCH  = FOCK_DIM / ROWS_PER_BLK; // 582 (exact)
constexpr int NBLK           = B * BLK_PER_BATCH;       // 4656
constexpr int BLOCK          = 1024;      // 4 slices x 256 threads

typedef float f32x4 __attribute__((ext_vector_type(4)));
typedef int   i32x4 __attribute__((ext_vector_type(4)));

// --- build inverse map: inv[f] = i such that fock_idx[i]==f, else -1 ---
__global__ __launch_bounds__(256) void init_inv_kernel(int* __restrict__ inv) {
    int i = blockIdx.x * 256 + threadIdx.x;
    if (i < FOCK_DIM) inv[i] = -1;
}

__global__ __launch_bounds__(256) void fill_inv_kernel(const int* __restrict__ fock_idx,
                                                       int* __restrict__ inv) {
    int i = blockIdx.x * 256 + threadIdx.x;
    if (i < N) inv[fock_idx[i]] = i;
}

// --- main kernel: 1024-thread block = 4 independent 256-thread slices,
//     each slice owns 2 consecutive output rows of one batch.
// Per row: one uniform early-prefetched inv[r]; dead row -> constant zero
// burst (R1's proven store morphology); live row -> L1 gather of the 4 KB
// input row. No LDS, no syncthreads, no nontemporal stores.
__global__ __launch_bounds__(BLOCK) void scatter8_kernel(
    const float* __restrict__ in,
    const int*   __restrict__ inv,
    float*       __restrict__ out) {

    const int tid   = threadIdx.x;
    const int slice = tid >> 8;            // 0..3
    const int t     = tid & 255;
    const int blk   = blockIdx.x;
    const int b     = blk / BLK_PER_BATCH; // 0..7 (magic-mul)
    const int rbase = (blk - b * BLK_PER_BATCH) * ROWS_PER_BLK + slice * 2;

    // prefetch liveness for both rows up-front (independent loads, one stall)
    const int x0 = inv[rbase + 0];
    const int x1 = inv[rbase + 1];

    const i32x4* __restrict__ inv4 = reinterpret_cast<const i32x4*>(inv);
    const float* __restrict__ ibat = in + (size_t)b * N * N;
    f32x4* __restrict__ obase = reinterpret_cast<f32x4*>(out)
        + ((size_t)b * FOCK_DIM + (size_t)rbase) * ROW_VEC;

    const int xs[2] = {x0, x1};
    #pragma unroll
    for (int k = 0; k < 2; ++k) {
        f32x4* __restrict__ orow = obase + (size_t)k * ROW_VEC;
        const int x = xs[k];               // static index (fully unrolled)
        if (x < 0) {
            const f32x4 z = {0.f, 0.f, 0.f, 0.f};
            for (int c4 = t; c4 < ROW_VEC; c4 += 256) orow[c4] = z;
        } else {
            const float* __restrict__ irow = ibat + (size_t)x * N;
            for (int c4 = t; c4 < ROW_VEC; c4 += 256) {
                const i32x4 iv = inv4[c4];
                f32x4 v;
                v.x = (iv.x >= 0) ? irow[iv.x] : 0.f;
                v.y = (iv.y >= 0) ? irow[iv.y] : 0.f;
                v.z = (iv.z >= 0) ? irow[iv.z] : 0.f;
                v.w = (iv.w >= 0) ? irow[iv.w] : 0.f;
                orow[c4] = v;
            }
        }
    }
}

extern "C" void kernel_launch(void* const* d_in, const int* in_sizes, int n_in,
                              void* d_out, int out_size, void* d_ws, size_t ws_size,
                              hipStream_t stream) {
    const float* in       = (const float*)d_in[0];   // [B, 1024, 1024] fp32
    const int*   fock_idx = (const int*)d_in[1];     // [1024] int32
    float*       out      = (float*)d_out;           // [B, 4656, 4656] fp32
    int*         inv      = (int*)d_ws;              // 4656 int32 scratch

    init_inv_kernel<<<(FOCK_DIM + 255) / 256, 256, 0, stream>>>(inv);
    fill_inv_kernel<<<(N + 255) / 256, 256, 0, stream>>>(fock_idx, inv);
    scatter8_kernel<<<NBLK, BLOCK, 0, stream>>>(in, inv, out);
}